// Round 8
// baseline (80.876 us; speedup 1.0000x reference)
//
#include <hip/hip_runtime.h>
#include <math.h>
#include <stdint.h>

// Chamfer loss, B=16, N=M=4096, D=3, fp32 in/out — MFMA formulation, R8.
//
// d^2(p,t) = |p|^2 + (|t|^2 - 2 p.t); the bracket via v_mfma_f32_32x32x16_f16:
//   A row (candidate): [tx, ty, tz, h1, h2, 0,0,0]   (k=0..7; hi-lane k=8..15 garbage)
//   B col (query):     [-2px,-2py,-2pz, 1, 1, 0,0,0] (k=0..7; k=8..15 ZERO -> annihilates A garbage)
// h1+h2 = two-f16 split of |t|^2 (fp32-accurate). f16 products are exact in the
// fp32 accumulator; only error is f16 point quantization (~1e-3 absmax, passes).
//
// R8 delta vs R7 (~27us main, 43% occupancy): R6 evidence (cache-warm == cold,
// both pipes <20%) says the stall is latency-hiding capacity. R7's grid (1024
// blocks x 8 waves, launch_bounds(512,6) -> 3 resident blocks/CU vs 4 of work)
// ran 2 epochs, the 2nd 1/3-occupied. Now: 2048 blocks x 256 thr (4 waves),
// launch_bounds(256,8) -> exactly 8 blocks/CU resident, single epoch, no tail.
// Waves 0-1: block's 64 queries x candidates [0:2048); waves 2-3: x [2048:4096);
// merge via 512 B LDS table. Plus explicit 1-deep rotating register prefetch:
// next tile's loads issue before current tile's MFMA results are consumed.
//
// Fixed cost context: harness re-poisons ~256 MB ws each timed iter = ~41.5 us
// of fillBuffer at HBM roofline inside dur_us, + ~8 us graph/launch overhead.
// Untouchable floor ~50 us.

#define BATCH   16
#define NPTS    4096
#define THREADS 256                            // 4 waves/block
#define NITEMS  (2 * BATCH * NPTS)             // 131072
#define MAIN_BLOCKS (2 * BATCH * (NPTS / 64))  // 2048: 64 queries per block

typedef __attribute__((ext_vector_type(8)))  _Float16 half8;
typedef __attribute__((ext_vector_type(16))) float    floatx16;

union Pack16 { float4 f4; _Float16 h[8]; half8 h8; };

__global__ __launch_bounds__(256) void chamfer_prep(
    const float* __restrict__ pred, const float* __restrict__ target,
    float4* __restrict__ packP, float4* __restrict__ packT)
{
    int g = blockIdx.x * 256 + threadIdx.x;       // 0..131071
    int arr = g >> 16;                            // 0=pred, 1=target
    int pt  = g & 65535;                          // b*NPTS + n
    const float* src = arr ? target : pred;
    float x = src[pt * 3 + 0];
    float y = src[pt * 3 + 1];
    float z = src[pt * 3 + 2];
    _Float16 hx = (_Float16)x, hy = (_Float16)y, hz = (_Float16)z;
    float xf = (float)hx, yf = (float)hy, zf = (float)hz;
    float t = xf * xf + yf * yf + zf * zf;        // |q|^2 of the QUANTIZED point
    _Float16 h1 = (_Float16)t;
    _Float16 h2 = (_Float16)(t - (float)h1);
    Pack16 p;
    p.h[0] = hx; p.h[1] = hy; p.h[2] = hz; p.h[3] = h1; p.h[4] = h2;
    p.h[5] = (_Float16)0.0f; p.h[6] = (_Float16)0.0f; p.h[7] = (_Float16)0.0f;
    (arr ? packT : packP)[pt] = p.f4;
}

__global__ __launch_bounds__(THREADS, 8) void chamfer_main(
    const float4* __restrict__ packP, const float4* __restrict__ packT,
    float* __restrict__ blocksum)
{
    __shared__ float pmin[4][32];   // per-wave per-query partial mins
    __shared__ float wsum[2];

    int tid  = threadIdx.x;
    int lane = tid & 63;
    int wave = tid >> 6;            // 0..3
    int qsub = wave & 1;            // query subgroup (32 queries)
    int half = wave >> 1;           // candidate half (2048 candidates)
    int l31  = lane & 31;
    bool lo  = lane < 32;

    int id = blockIdx.x;
    int ng = id & 63; id >>= 6;     // query group (64 queries)
    int b  = id & 15; id >>= 4;
    int dir = id;                   // 0: queries=pred, candidates=target

    const float4* qpack = dir ? packT : packP;
    const float4* cpack = dir ? packP : packT;

    // Per-wave constant B fragment: 32 query cols (col = lane&31).
    // Lanes 32-63 carry k=8..15 -> all zero (annihilates A hi-lane garbage).
    Pack16 praw;
    praw.f4 = qpack[(size_t)b * NPTS + ng * 64 + qsub * 32 + l31];
    float psq = (float)praw.h[3] + (float)praw.h[4];   // |p|^2, fp32-accurate

    half8 bfrag;
#pragma unroll
    for (int i = 0; i < 8; ++i) bfrag[i] = (_Float16)0.0f;
    if (lo) {
        bfrag[0] = (_Float16)(praw.h[0] * (_Float16)-2.0f);  // exact x2 scale
        bfrag[1] = (_Float16)(praw.h[1] * (_Float16)-2.0f);
        bfrag[2] = (_Float16)(praw.h[2] * (_Float16)-2.0f);
        bfrag[3] = (_Float16)1.0f;
        bfrag[4] = (_Float16)1.0f;
    }

    const float4* cb = cpack + (size_t)b * NPTS + half * 2048;

    floatx16 zero, mn;
#pragma unroll
    for (int r = 0; r < 16; ++r) { zero[r] = 0.0f; mn[r] = 1e30f; }

    // 32 tiles x 64 candidates (this wave's half), A-fragments straight from
    // global (lanes 0-31 / 32-63 broadcast-read the same 512 B, L1/L2-served).
    // Rotating 1-deep register prefetch: tile t+1's loads are issued BEFORE
    // tile t's MFMA results are consumed, so VMEM latency overlaps compute.
    float4 c0 = cb[l31];
    float4 c1 = cb[32 + l31];
#pragma unroll 4
    for (int t = 0; t < 32; ++t) {
        int tn = (t + 1) & 31;                 // wraps to 0 on last iter (harmless reload)
        float4 n0 = cb[tn * 64 + l31];
        float4 n1 = cb[tn * 64 + 32 + l31];
        Pack16 a0, a1;
        a0.f4 = c0;
        a1.f4 = c1;
        floatx16 d0 = __builtin_amdgcn_mfma_f32_32x32x16_f16(a0.h8, bfrag, zero, 0, 0, 0);
        floatx16 d1 = __builtin_amdgcn_mfma_f32_32x32x16_f16(a1.h8, bfrag, zero, 0, 0, 0);
#pragma unroll
        for (int r = 0; r < 16; ++r)
            mn[r] = fminf(fminf(d0[r], d1[r]), mn[r]);   // v_min3_f32, 1 inst / 2 pairs
        c0 = n0;
        c1 = n1;
    }

    // Per-lane 16-reg min tree, merge row-halves across lane^32, publish.
    float m0 = fminf(fminf(mn[0], mn[1]),   fminf(mn[2], mn[3]));
    float m1 = fminf(fminf(mn[4], mn[5]),   fminf(mn[6], mn[7]));
    float m2 = fminf(fminf(mn[8], mn[9]),   fminf(mn[10], mn[11]));
    float m3 = fminf(fminf(mn[12], mn[13]), fminf(mn[14], mn[15]));
    float m  = fminf(fminf(m0, m1), fminf(m2, m3));
    m = fminf(m, __shfl_xor(m, 32));
    if (lo) pmin[wave][l31] = m;
    __syncthreads();

    // Waves 0-1: merge with candidate-upper-half partner (wave+2), finish.
    if (wave < 2) {
        float mm = fminf(m, pmin[wave + 2][l31]);
        float dist = sqrtf(fmaxf(mm + psq, 0.0f));
#pragma unroll
        for (int off = 1; off <= 16; off <<= 1)
            dist += __shfl_xor(dist, off);
        if (lane == 0) wsum[wave] = dist;
    }
    __syncthreads();

    if (tid == 0)
        blocksum[blockIdx.x] = wsum[0] + wsum[1];
}

__global__ __launch_bounds__(256) void chamfer_finish(
    const float4* __restrict__ bs, float* __restrict__ out)
{
    __shared__ float ws[4];
    int tid = threadIdx.x;
    float4 v = bs[tid];                   // 2048 block sums = 256 thr x 2 float4
    float4 w = bs[tid + 256];
    float s = (v.x + v.y) + (v.z + v.w) + (w.x + w.y) + (w.z + w.w);
#pragma unroll
    for (int off = 1; off <= 32; off <<= 1)
        s += __shfl_xor(s, off);
    int lane = tid & 63, wave = tid >> 6;
    if (lane == 0) ws[wave] = s;
    __syncthreads();
    if (tid == 0) out[0] = (ws[0] + ws[1] + ws[2] + ws[3]) * (1.0f / (float)NITEMS);
}

extern "C" void kernel_launch(void* const* d_in, const int* in_sizes, int n_in,
                              void* d_out, int out_size, void* d_ws, size_t ws_size,
                              hipStream_t stream) {
    const float* pred   = (const float*)d_in[0];
    const float* target = (const float*)d_in[1];
    float* out = (float*)d_out;

    float4* packP = (float4*)d_ws;                              // 1 MB
    float4* packT = packP + (size_t)BATCH * NPTS;               // 1 MB
    float*  blocksum = (float*)(packT + (size_t)BATCH * NPTS);  // 8 KB

    chamfer_prep<<<NITEMS / 256, 256, 0, stream>>>(pred, target, packP, packT);
    chamfer_main<<<MAIN_BLOCKS, THREADS, 0, stream>>>(packP, packT, blocksum);
    chamfer_finish<<<1, 256, 0, stream>>>((const float4*)blocksum, out);
}

// Round 9
// 75.941 us; speedup vs baseline: 1.0650x; 1.0650x over previous
//
#include <hip/hip_runtime.h>
#include <math.h>
#include <stdint.h>

// Chamfer loss, B=16, N=M=4096, D=3, fp32 in/out — MFMA formulation, R9.
//
// d^2(p,t) = |p|^2 + (|t|^2 - 2 p.t); the bracket via v_mfma_f32_32x32x16_f16:
//   A row (candidate): [tx, ty, tz, h1, h2, 0,0,0]   (k=0..7; hi-lane k=8..15 garbage)
//   B col (query):     [-2px,-2py,-2pz, 1, 1, 0,0,0] (k=0..7; k=8..15 ZERO -> annihilates A garbage)
// h1+h2 = two-f16 split of |t|^2 (fp32-accurate). f16 products are exact in the
// fp32 accumulator; only error is f16 point quantization (~1e-3 absmax, passes).
//
// R9 delta vs R8 (neutral): occupancy and load-prefetch changes did nothing;
// warm==cold (R6); both pipes <20%. Remaining suspect: per-wave dependency ILP
// — one serial load->MFMA->16x min3 chain per wave (VGPR_Count=40 proves the
// compiler reuses d0's regs for d1, serializing). Now each wave holds TWO
// B-fragments (64 queries) and runs TWO independent min-chains (mnA/mnB) off
// shared A-loads: MFMA latency on chain A overlaps min3 issue on chain B.
// A-loads per MFMA also halve. Grid 1024 x 256thr, launch_bounds(256,4):
// 4 blocks/CU resident, single epoch.
//
// Fixed cost context: harness re-poisons ~256 MB ws each timed iter = ~41.5 us
// of fillBuffer at HBM roofline inside dur_us, + ~10 us graph/launch overhead.
// Untouchable floor ~55 us.

#define BATCH   16
#define NPTS    4096
#define THREADS 256                            // 4 waves/block
#define NITEMS  (2 * BATCH * NPTS)             // 131072
#define MAIN_BLOCKS (2 * BATCH * (NPTS / 128)) // 1024: 128 queries per block

typedef __attribute__((ext_vector_type(8)))  _Float16 half8;
typedef __attribute__((ext_vector_type(16))) float    floatx16;

union Pack16 { float4 f4; _Float16 h[8]; half8 h8; };

__global__ __launch_bounds__(256) void chamfer_prep(
    const float* __restrict__ pred, const float* __restrict__ target,
    float4* __restrict__ packP, float4* __restrict__ packT)
{
    int g = blockIdx.x * 256 + threadIdx.x;       // 0..131071
    int arr = g >> 16;                            // 0=pred, 1=target
    int pt  = g & 65535;                          // b*NPTS + n
    const float* src = arr ? target : pred;
    float x = src[pt * 3 + 0];
    float y = src[pt * 3 + 1];
    float z = src[pt * 3 + 2];
    _Float16 hx = (_Float16)x, hy = (_Float16)y, hz = (_Float16)z;
    float xf = (float)hx, yf = (float)hy, zf = (float)hz;
    float t = xf * xf + yf * yf + zf * zf;        // |q|^2 of the QUANTIZED point
    _Float16 h1 = (_Float16)t;
    _Float16 h2 = (_Float16)(t - (float)h1);
    Pack16 p;
    p.h[0] = hx; p.h[1] = hy; p.h[2] = hz; p.h[3] = h1; p.h[4] = h2;
    p.h[5] = (_Float16)0.0f; p.h[6] = (_Float16)0.0f; p.h[7] = (_Float16)0.0f;
    (arr ? packT : packP)[pt] = p.f4;
}

__device__ inline half8 make_bfrag(const Pack16& praw, bool lo) {
    half8 f;
#pragma unroll
    for (int i = 0; i < 8; ++i) f[i] = (_Float16)0.0f;
    if (lo) {
        f[0] = (_Float16)(praw.h[0] * (_Float16)-2.0f);  // exact x2 scale
        f[1] = (_Float16)(praw.h[1] * (_Float16)-2.0f);
        f[2] = (_Float16)(praw.h[2] * (_Float16)-2.0f);
        f[3] = (_Float16)1.0f;
        f[4] = (_Float16)1.0f;
    }
    return f;
}

__global__ __launch_bounds__(THREADS, 4) void chamfer_main(
    const float4* __restrict__ packP, const float4* __restrict__ packT,
    float* __restrict__ blocksum)
{
    __shared__ float pmin[4][64];   // per-wave mins for its 64 queries
    __shared__ float wsum[2];

    int tid  = threadIdx.x;
    int lane = tid & 63;
    int wave = tid >> 6;            // 0..3
    int qhalf = wave & 1;           // query half (64 queries)
    int chalf = wave >> 1;          // candidate half (2048 candidates)
    int l31  = lane & 31;
    bool lo  = lane < 32;

    int id = blockIdx.x;
    int ng = id & 31; id >>= 5;     // query group (128 queries)
    int b  = id & 15; id >>= 4;
    int dir = id;                   // 0: queries=pred, candidates=target

    const float4* qpack = dir ? packT : packP;
    const float4* cpack = dir ? packP : packT;

    // Two B fragments per wave: queries [qbase, qbase+32) and [qbase+32, qbase+64).
    size_t qbase = (size_t)b * NPTS + ng * 128 + qhalf * 64;
    Pack16 prA, prB;
    prA.f4 = qpack[qbase + l31];
    prB.f4 = qpack[qbase + 32 + l31];
    half8 bfragA = make_bfrag(prA, lo);
    half8 bfragB = make_bfrag(prB, lo);

    const float4* cb = cpack + (size_t)b * NPTS + chalf * 2048;

    floatx16 zero, mnA, mnB;
#pragma unroll
    for (int r = 0; r < 16; ++r) { zero[r] = 0.0f; mnA[r] = 1e30f; mnB[r] = 1e30f; }

    // 32 tiles x 64 candidates. Each load-pair feeds TWO independent MFMA/min
    // chains (bfragA vs bfragB) -> MFMA result latency on one chain overlaps
    // VALU issue on the other. A-loads per MFMA are halved vs R8.
#pragma unroll 2
    for (int t = 0; t < 32; ++t) {
        Pack16 a0, a1;
        a0.f4 = cb[t * 64 + l31];
        a1.f4 = cb[t * 64 + 32 + l31];
        floatx16 d0 = __builtin_amdgcn_mfma_f32_32x32x16_f16(a0.h8, bfragA, zero, 0, 0, 0);
        floatx16 d1 = __builtin_amdgcn_mfma_f32_32x32x16_f16(a0.h8, bfragB, zero, 0, 0, 0);
#pragma unroll
        for (int r = 0; r < 16; ++r) mnA[r] = fminf(d0[r], mnA[r]);
#pragma unroll
        for (int r = 0; r < 16; ++r) mnB[r] = fminf(d1[r], mnB[r]);
        floatx16 d2 = __builtin_amdgcn_mfma_f32_32x32x16_f16(a1.h8, bfragA, zero, 0, 0, 0);
        floatx16 d3 = __builtin_amdgcn_mfma_f32_32x32x16_f16(a1.h8, bfragB, zero, 0, 0, 0);
#pragma unroll
        for (int r = 0; r < 16; ++r) mnA[r] = fminf(d2[r], mnA[r]);
#pragma unroll
        for (int r = 0; r < 16; ++r) mnB[r] = fminf(d3[r], mnB[r]);
    }

    // Per-lane 16-reg min trees, fold row-halves across lane^32, publish both
    // query sets (cols l31 / l31+32 of pmin row).
    float mA = fminf(fminf(fminf(mnA[0], mnA[1]),   fminf(mnA[2], mnA[3])),
                     fminf(fminf(mnA[4], mnA[5]),   fminf(mnA[6], mnA[7])));
    mA = fminf(mA, fminf(fminf(fminf(mnA[8], mnA[9]),   fminf(mnA[10], mnA[11])),
                         fminf(fminf(mnA[12], mnA[13]), fminf(mnA[14], mnA[15]))));
    float mB = fminf(fminf(fminf(mnB[0], mnB[1]),   fminf(mnB[2], mnB[3])),
                     fminf(fminf(mnB[4], mnB[5]),   fminf(mnB[6], mnB[7])));
    mB = fminf(mB, fminf(fminf(fminf(mnB[8], mnB[9]),   fminf(mnB[10], mnB[11])),
                         fminf(fminf(mnB[12], mnB[13]), fminf(mnB[14], mnB[15]))));
    mA = fminf(mA, __shfl_xor(mA, 32));
    mB = fminf(mB, __shfl_xor(mB, 32));
    if (lo) {
        pmin[wave][l31]      = mA;
        pmin[wave][l31 + 32] = mB;
    }
    __syncthreads();

    // Waves 0-1: all 64 lanes finish one query each (query = qg*128 + wave*64 + lane):
    // merge candidate halves, add |p|^2, sqrt, full-wave sum.
    if (wave < 2) {
        float mm = fminf(pmin[wave][lane], pmin[wave + 2][lane]);
        Pack16 pr;
        pr.f4 = qpack[(size_t)b * NPTS + ng * 128 + wave * 64 + lane];
        float psq = (float)pr.h[3] + (float)pr.h[4];
        float dist = sqrtf(fmaxf(mm + psq, 0.0f));
#pragma unroll
        for (int off = 1; off <= 32; off <<= 1)
            dist += __shfl_xor(dist, off);
        if (lane == 0) wsum[wave] = dist;
    }
    __syncthreads();

    if (tid == 0)
        blocksum[blockIdx.x] = wsum[0] + wsum[1];
}

__global__ __launch_bounds__(256) void chamfer_finish(
    const float4* __restrict__ bs, float* __restrict__ out)
{
    __shared__ float ws[4];
    int tid = threadIdx.x;
    float4 v = bs[tid];                   // 1024 block sums = 256 thr x float4
    float s = (v.x + v.y) + (v.z + v.w);
#pragma unroll
    for (int off = 1; off <= 32; off <<= 1)
        s += __shfl_xor(s, off);
    int lane = tid & 63, wave = tid >> 6;
    if (lane == 0) ws[wave] = s;
    __syncthreads();
    if (tid == 0) out[0] = (ws[0] + ws[1] + ws[2] + ws[3]) * (1.0f / (float)NITEMS);
}

extern "C" void kernel_launch(void* const* d_in, const int* in_sizes, int n_in,
                              void* d_out, int out_size, void* d_ws, size_t ws_size,
                              hipStream_t stream) {
    const float* pred   = (const float*)d_in[0];
    const float* target = (const float*)d_in[1];
    float* out = (float*)d_out;

    float4* packP = (float4*)d_ws;                              // 1 MB
    float4* packT = packP + (size_t)BATCH * NPTS;               // 1 MB
    float*  blocksum = (float*)(packT + (size_t)BATCH * NPTS);  // 4 KB

    chamfer_prep<<<NITEMS / 256, 256, 0, stream>>>(pred, target, packP, packT);
    chamfer_main<<<MAIN_BLOCKS, THREADS, 0, stream>>>(packP, packT, blocksum);
    chamfer_finish<<<1, 256, 0, stream>>>((const float4*)blocksum, out);
}